// Round 5
// baseline (198.759 us; speedup 1.0000x reference)
//
#include <hip/hip_runtime.h>
#include <math.h>

#define T_TOKENS 8192
#define NEXP 256
#define DIM 7168
#define NEG_INF (-3.0e38f)

typedef _Float16 f16;
typedef _Float16 f16x8 __attribute__((ext_vector_type(8)));
typedef __fp16 h16x2 __attribute__((ext_vector_type(2)));
typedef float f32x4 __attribute__((ext_vector_type(4)));
typedef float f32x16 __attribute__((ext_vector_type(16)));

#define AS1 __attribute__((address_space(1)))
#define AS3 __attribute__((address_space(3)))

// ws layout: [W' tiled f16 planes 7.34MB][part f32 (nsplit x T x E)]
// W' = 448 chunks of 16KB, chunk = (k_global/32)*2 + bn.
// chunk image == LDS image: off = ((ksub*2+p)*4 + ncol32)*1024 + (k8&1)*512 + e*16 + i*2
#define WTILED_BYTES (2 * NEXP * DIM * 2)      // 7,340,032
#define PART_OFF WTILED_BYTES
#define UNSCALE 5.9604644775390625e-8f         // 2^-24 exact

// ---------------- prologue: w (f32) -> tiled 2-plane f16 image ----------------
__global__ __launch_bounds__(256) void wconvert(const float* __restrict__ w,
                                                char* __restrict__ wt) {
    const int n = blockIdx.x * 256 + threadIdx.x;   // 0 .. 229375
    const int K8 = n % 896;                         // k-octet
    const int eg = n / 896;                         // expert 0..255
    const f32x4 u0 = *(const f32x4*)(w + eg * DIM + K8 * 8);
    const f32x4 u1 = *(const f32x4*)(w + eg * DIM + K8 * 8 + 4);
    float c[8] = {u0[0]*4096.f, u0[1]*4096.f, u0[2]*4096.f, u0[3]*4096.f,
                  u1[0]*4096.f, u1[1]*4096.f, u1[2]*4096.f, u1[3]*4096.f};
    f16x8 h, g;
#pragma unroll
    for (int j = 0; j < 4; ++j) {
        h16x2 hp = __builtin_amdgcn_cvt_pkrtz(c[2*j], c[2*j+1]);
        float r0 = c[2*j]   - (float)hp[0];
        float r1 = c[2*j+1] - (float)hp[1];
        h16x2 gp = __builtin_amdgcn_cvt_pkrtz(r0, r1);
        h[2*j] = (f16)hp[0]; h[2*j+1] = (f16)hp[1];
        g[2*j] = (f16)gp[0]; g[2*j+1] = (f16)gp[1];
    }
    const int T = K8 >> 2, ksub = (K8 >> 1) & 1, kch = K8 & 1;
    const int bn = eg >> 7, E = eg & 127, np_ = E >> 5, e = E & 31;
    const int base = (T * 2 + bn) * 16384 + kch * 512 + e * 16;
    *(f16x8*)(wt + base + ((ksub * 2 + 0) * 4 + np_) * 1024) = h;
    *(f16x8*)(wt + base + ((ksub * 2 + 1) * 4 + np_) * 1024) = g;
}

// ---------------- GEMM: A global->reg, W' LDS, 32x32x16 f16, 4-product ----------------
// grid (2=bn, 64=bm, nsplit), block 256 (4 waves 2x2), wave tile 64x64
__global__ __launch_bounds__(256) void gemm32(
    const float* __restrict__ x, const char* __restrict__ wt,
    float* __restrict__ part, int ksplit) {
    __shared__ char smem[32768];                   // 2 x 16KB W double-buffer
    const int tid = threadIdx.x;
    const int lane = tid & 63;
    const int wv = tid >> 6;
    const int bn = blockIdx.x, bm = blockIdx.y, bz = blockIdx.z;
    const int wr = wv >> 1, wcn = wv & 1;
    const int l31 = lane & 31, lhi = lane >> 5;

    // A row base pointers (per m' subtile), include bz k-offset and lane k-sub
    const float* arow[2];
#pragma unroll
    for (int mp = 0; mp < 2; ++mp)
        arow[mp] = x + (size_t)(bm * 128 + wr * 64 + mp * 32 + l31) * DIM
                 + bz * ksplit + lhi * 8;

    // W stage: 4 gll per wave, linear 1KB each
    const int niter = ksplit >> 5;
    const char* wsrc = wt + (size_t)(bz * niter * 2 + bn) * 16384 + (wv * 4) * 1024 + lane * 16;
    const int ldsw = (wv * 4) * 1024;

    // W fragment read offsets: contiguous 1KB per (ksub, plane, n')
    int rW[2][2][2];
#pragma unroll
    for (int ks = 0; ks < 2; ++ks)
#pragma unroll
        for (int p = 0; p < 2; ++p)
#pragma unroll
            for (int np_ = 0; np_ < 2; ++np_)
                rW[ks][p][np_] = ((ks * 2 + p) * 4 + (wcn * 2 + np_)) * 1024
                               + lhi * 512 + l31 * 16;

    f32x16 acc[2][2];
#pragma unroll
    for (int mp = 0; mp < 2; ++mp)
#pragma unroll
        for (int np_ = 0; np_ < 2; ++np_)
#pragma unroll
            for (int r = 0; r < 16; ++r) acc[mp][np_][r] = 0.0f;

    f32x4 ab[2][2][2];   // [m'][ksub][pair]

#define LOAD_A(koff)                                                            \
    {                                                                           \
        _Pragma("unroll")                                                       \
        for (int mp = 0; mp < 2; ++mp)                                          \
            _Pragma("unroll")                                                   \
            for (int ks = 0; ks < 2; ++ks) {                                    \
                ab[mp][ks][0] = *(const f32x4*)(arow[mp] + (koff) + ks * 16);   \
                ab[mp][ks][1] = *(const f32x4*)(arow[mp] + (koff) + ks * 16 + 4);\
            }                                                                   \
    }

#define STAGE_W(t, sb)                                                          \
    {                                                                           \
        const char* s_ = wsrc + (size_t)(t) * 32768;                            \
        _Pragma("unroll")                                                       \
        for (int i = 0; i < 4; ++i)                                             \
            __builtin_amdgcn_global_load_lds((const AS1 void*)(s_ + i * 1024),  \
                (AS3 void*)(smem + (sb) + ldsw + i * 1024), 16, 0, 0);          \
    }

#define CONVERT()                                                               \
    f16x8 fa0[2][2], fa1[2][2];                                                 \
    {                                                                           \
        _Pragma("unroll")                                                       \
        for (int mp = 0; mp < 2; ++mp)                                          \
            _Pragma("unroll")                                                   \
            for (int ks = 0; ks < 2; ++ks) {                                    \
                float c[8] = {ab[mp][ks][0][0]*4096.f, ab[mp][ks][0][1]*4096.f, \
                              ab[mp][ks][0][2]*4096.f, ab[mp][ks][0][3]*4096.f, \
                              ab[mp][ks][1][0]*4096.f, ab[mp][ks][1][1]*4096.f, \
                              ab[mp][ks][1][2]*4096.f, ab[mp][ks][1][3]*4096.f};\
                _Pragma("unroll")                                               \
                for (int j = 0; j < 4; ++j) {                                   \
                    h16x2 hp = __builtin_amdgcn_cvt_pkrtz(c[2*j], c[2*j+1]);    \
                    float r0 = c[2*j]   - (float)hp[0];                         \
                    float r1 = c[2*j+1] - (float)hp[1];                         \
                    h16x2 gp = __builtin_amdgcn_cvt_pkrtz(r0, r1);              \
                    fa0[mp][ks][2*j] = (f16)hp[0]; fa0[mp][ks][2*j+1] = (f16)hp[1]; \
                    fa1[mp][ks][2*j] = (f16)gp[0]; fa1[mp][ks][2*j+1] = (f16)gp[1]; \
                }                                                               \
            }                                                                   \
    }

#define MFMA_STEP(sb)                                                           \
    {                                                                           \
        __builtin_amdgcn_s_setprio(1);                                          \
        _Pragma("unroll")                                                       \
        for (int ks = 0; ks < 2; ++ks)                                          \
            _Pragma("unroll")                                                   \
            for (int np_ = 0; np_ < 2; ++np_) {                                 \
                const f16x8 wb0 = *(const f16x8*)(smem + (sb) + rW[ks][0][np_]);\
                const f16x8 wb1 = *(const f16x8*)(smem + (sb) + rW[ks][1][np_]);\
                _Pragma("unroll")                                               \
                for (int mp = 0; mp < 2; ++mp) {                                \
                    acc[mp][np_] = __builtin_amdgcn_mfma_f32_32x32x16_f16(fa0[mp][ks], wb0, acc[mp][np_], 0, 0, 0); \
                    acc[mp][np_] = __builtin_amdgcn_mfma_f32_32x32x16_f16(fa1[mp][ks], wb0, acc[mp][np_], 0, 0, 0); \
                    acc[mp][np_] = __builtin_amdgcn_mfma_f32_32x32x16_f16(fa0[mp][ks], wb1, acc[mp][np_], 0, 0, 0); \
                    acc[mp][np_] = __builtin_amdgcn_mfma_f32_32x32x16_f16(fa1[mp][ks], wb1, acc[mp][np_], 0, 0, 0); \
                }                                                               \
            }                                                                   \
        __builtin_amdgcn_s_setprio(0);                                          \
    }

    // prologue: A(0) then W(0)  -> outstanding [A0(8), W0(4)]
    LOAD_A(0);
    STAGE_W(0, 0);

    for (int t = 0; t < niter - 1; ++t) {
        const int cur = (t & 1) * 16384;
        const int nxt = ((t + 1) & 1) * 16384;
        asm volatile("s_waitcnt vmcnt(4)" ::: "memory");   // A(t) regs ready
        __builtin_amdgcn_sched_barrier(0);
        CONVERT();                                          // uses ab -> frags
        LOAD_A((t + 1) * 32);                               // overwrite ab (WAR ok)
        STAGE_W(t + 1, nxt);
        asm volatile("s_waitcnt vmcnt(12)" ::: "memory");  // W(t) landed in LDS
        __builtin_amdgcn_sched_barrier(0);
        __builtin_amdgcn_s_barrier();
        MFMA_STEP(cur);
        __builtin_amdgcn_s_barrier();                       // reads done before restage
    }
    {
        const int cur = ((niter - 1) & 1) * 16384;
        asm volatile("s_waitcnt vmcnt(4)" ::: "memory");
        __builtin_amdgcn_sched_barrier(0);
        CONVERT();
        asm volatile("s_waitcnt vmcnt(0)" ::: "memory");
        __builtin_amdgcn_sched_barrier(0);
        __builtin_amdgcn_s_barrier();
        MFMA_STEP(cur);
    }
#undef LOAD_A
#undef STAGE_W
#undef CONVERT
#undef MFMA_STEP

    // epilogue: scaled partials; C layout col=l31, row=(r&3)+8*(r>>2)+4*lhi
    float* P = part + (size_t)bz * T_TOKENS * NEXP;
#pragma unroll
    for (int mp = 0; mp < 2; ++mp)
#pragma unroll
        for (int np_ = 0; np_ < 2; ++np_) {
            const int gcol = bn * 128 + (wcn * 2 + np_) * 32 + l31;
#pragma unroll
            for (int r = 0; r < 16; ++r) {
                const int row32 = (r & 3) + 8 * (r >> 2) + 4 * lhi;
                const int grow = bm * 128 + wr * 64 + mp * 32 + row32;
                P[(size_t)grow * NEXP + gcol] = acc[mp][np_][r];
            }
        }
}

// ---------------- Routing: one wave per token (identical logic to R3/R4) ----------------
__global__ __launch_bounds__(256) void routing_kernel(const float* __restrict__ part,
                                                      const float* __restrict__ bias,
                                                      float* __restrict__ out, int nsplit) {
    const int lane = threadIdx.x & 63;
    const int t = blockIdx.x * 4 + (threadIdx.x >> 6);

    f32x4 z = {0.f, 0.f, 0.f, 0.f};
    for (int s = 0; s < nsplit; ++s) {
        const f32x4 v = *((const f32x4*)(part + ((size_t)s * T_TOKENS + t) * NEXP) + lane);
        z[0] += v[0]; z[1] += v[1]; z[2] += v[2]; z[3] += v[3];
    }
    const float s0 = 1.0f / (1.0f + expf(-z[0] * UNSCALE));
    const float s1 = 1.0f / (1.0f + expf(-z[1] * UNSCALE));
    const float s2 = 1.0f / (1.0f + expf(-z[2] * UNSCALE));
    const float s3 = 1.0f / (1.0f + expf(-z[3] * UNSCALE));
    const f32x4 bv = *((const f32x4*)bias + lane);
    float sb0 = s0 + bv[0], sb1 = s1 + bv[1], sb2 = s2 + bv[2], sb3 = s3 + bv[3];

    float m1, m2;
    m1 = sb0; m2 = NEG_INF;
    if (sb1 > m1) { m2 = m1; m1 = sb1; } else if (sb1 > m2) m2 = sb1;
    if (sb2 > m1) { m2 = m1; m1 = sb2; } else if (sb2 > m2) m2 = sb2;
    if (sb3 > m1) { m2 = m1; m1 = sb3; } else if (sb3 > m2) m2 = sb3;
#pragma unroll
    for (int off = 1; off < 8; off <<= 1) {
        const float om1 = __shfl_xor(m1, off);
        const float om2 = __shfl_xor(m2, off);
        const float hi = fmaxf(m1, om1);
        const float lo = fminf(m1, om1);
        m2 = fmaxf(lo, fmaxf(m2, om2));
        m1 = hi;
    }
    const float gs = m1 + m2;

    const float g0 = __shfl(gs, 0),  g1 = __shfl(gs, 8),  g2 = __shfl(gs, 16), g3 = __shfl(gs, 24);
    const float g4 = __shfl(gs, 32), g5 = __shfl(gs, 40), g6 = __shfl(gs, 48), g7 = __shfl(gs, 56);

    float t1 = NEG_INF, t2 = NEG_INF, t3 = NEG_INF, t4 = NEG_INF;
    int i1 = 0, i2 = 0, i3 = 0, i4 = 0;
#define INS4(v, gi)                                                         \
    {                                                                       \
        if (v > t1)      { t4=t3;i4=i3; t3=t2;i3=i2; t2=t1;i2=i1; t1=v;i1=gi; } \
        else if (v > t2) { t4=t3;i4=i3; t3=t2;i3=i2; t2=v;i2=gi; }          \
        else if (v > t3) { t4=t3;i4=i3; t3=v;i3=gi; }                       \
        else if (v > t4) { t4=v;i4=gi; }                                    \
    }
    INS4(g0, 0) INS4(g1, 1) INS4(g2, 2) INS4(g3, 3)
    INS4(g4, 4) INS4(g5, 5) INS4(g6, 6) INS4(g7, 7)
#undef INS4
    const int keepmask = (1 << i1) | (1 << i2) | (1 << i3) | (1 << i4);

    const int g = lane >> 3;
    if (!((keepmask >> g) & 1)) { sb0 = NEG_INF; sb1 = NEG_INF; sb2 = NEG_INF; sb3 = NEG_INF; }

    float wval[8];
    int wi[8];
    float wsum = 0.0f;
#pragma unroll
    for (int r = 0; r < 8; r++) {
        float bvv = sb0;
        int bii = (lane << 2);
        if (sb1 > bvv) { bvv = sb1; bii = (lane << 2) | 1; }
        if (sb2 > bvv) { bvv = sb2; bii = (lane << 2) | 2; }
        if (sb3 > bvv) { bvv = sb3; bii = (lane << 2) | 3; }
#pragma unroll
        for (int off = 1; off < 64; off <<= 1) {
            const float ov = __shfl_xor(bvv, off);
            const int oi = __shfl_xor(bii, off);
            if (ov > bvv || (ov == bvv && oi < bii)) { bvv = ov; bii = oi; }
        }
        const int sl = bii & 3;
        const float cand = (sl == 0) ? s0 : (sl == 1) ? s1 : (sl == 2) ? s2 : s3;
        const float ow = __shfl(cand, bii >> 2);
        wval[r] = ow;
        wi[r] = bii;
        wsum += ow;
        if ((bii >> 2) == lane) {
            if (sl == 0) sb0 = NEG_INF;
            else if (sl == 1) sb1 = NEG_INF;
            else if (sl == 2) sb2 = NEG_INF;
            else sb3 = NEG_INF;
        }
    }
    const float scale = 2.5f / wsum;
    if (lane == 0) {
        float* ow8 = out + (size_t)t * 8;
        float* oi8 = out + (size_t)T_TOKENS * 8 + (size_t)t * 8;
#pragma unroll
        for (int r = 0; r < 8; r++) {
            ow8[r] = wval[r] * scale;
            oi8[r] = (float)wi[r];
        }
    }
}

extern "C" void kernel_launch(void* const* d_in, const int* in_sizes, int n_in,
                              void* d_out, int out_size, void* d_ws, size_t ws_size,
                              hipStream_t stream) {
    const float* x = (const float*)d_in[0];
    const float* w = (const float*)d_in[1];
    const float* bias = (const float*)d_in[2];

    char* wt = (char*)d_ws;
    float* part = (float*)((char*)d_ws + PART_OFF);

    const size_t need4 = (size_t)PART_OFF + 4ull * T_TOKENS * NEXP * 4;
    const int nsplit = (ws_size >= need4) ? 4 : 2;
    const int ksplit = DIM / nsplit;

    wconvert<<<NEXP * DIM / (256 * 8), 256, 0, stream>>>(w, wt);
    gemm32<<<dim3(2, 64, nsplit), 256, 0, stream>>>(x, wt, part, ksplit);
    routing_kernel<<<T_TOKENS / 4, 256, 0, stream>>>(part, bias, (float*)d_out, nsplit);
}

// Round 6
// 179.669 us; speedup vs baseline: 1.1062x; 1.1062x over previous
//
#include <hip/hip_runtime.h>
#include <math.h>

#define T_TOKENS 8192
#define NEXP 256
#define DIM 7168
#define NEG_INF (-3.0e38f)

typedef _Float16 f16;
typedef _Float16 f16x8 __attribute__((ext_vector_type(8)));
typedef __fp16 h16x2 __attribute__((ext_vector_type(2)));
typedef float f32x4 __attribute__((ext_vector_type(4)));

#define AS1 __attribute__((address_space(1)))
#define AS3 __attribute__((address_space(3)))

// ws layout: [W' frag-tiled f16 7.34MB][part f32 (nsplit x T x E)]
// W' chunks of 8KB indexed by (T = k/32, bn = expert/64):
//   off_in_chunk = (p*4 + nt)*1024 + q*256 + l*16   (p=plane, nt=(e>>4)&3, q=(k>>3)&3, l=e&15)
// -> a wave ds_read_b128 at q4*256+l15*16 is 64 lanes x consecutive 16B: conflict-free,
//    and gll staging is 8 linear 1KB units.
#define WTILED_BYTES (2 * NEXP * DIM * 2)      // 7,340,032
#define PART_OFF WTILED_BYTES
#define UNSCALE 5.9604644775390625e-8f         // 2^-24 exact

// ---------------- prologue: w (f32) -> frag-tiled 2-plane f16 image ----------------
__global__ __launch_bounds__(256) void wconvert(const float* __restrict__ w,
                                                char* __restrict__ wt) {
    const int n = blockIdx.x * 256 + threadIdx.x;   // 0 .. 229375
    const int K8 = n % 896;                         // k-octet
    const int e = n / 896;                          // expert 0..255
    const f32x4 u0 = *(const f32x4*)(w + (size_t)e * DIM + K8 * 8);
    const f32x4 u1 = *(const f32x4*)(w + (size_t)e * DIM + K8 * 8 + 4);
    float c[8] = {u0[0]*4096.f, u0[1]*4096.f, u0[2]*4096.f, u0[3]*4096.f,
                  u1[0]*4096.f, u1[1]*4096.f, u1[2]*4096.f, u1[3]*4096.f};
    f16x8 h, g;
#pragma unroll
    for (int j = 0; j < 4; ++j) {
        h16x2 hp = __builtin_amdgcn_cvt_pkrtz(c[2*j], c[2*j+1]);
        float r0 = c[2*j]   - (float)hp[0];
        float r1 = c[2*j+1] - (float)hp[1];
        h16x2 gp = __builtin_amdgcn_cvt_pkrtz(r0, r1);
        h[2*j] = (f16)hp[0]; h[2*j+1] = (f16)hp[1];
        g[2*j] = (f16)gp[0]; g[2*j+1] = (f16)gp[1];
    }
    const int T = K8 >> 2, q = K8 & 3;
    const int bn = e >> 6, nt = (e >> 4) & 3, l = e & 15;
    char* base = wt + ((size_t)(T * 4 + bn)) * 8192 + q * 256 + l * 16;
    *(f16x8*)(base + (0 * 4 + nt) * 1024) = h;
    *(f16x8*)(base + (1 * 4 + nt) * 1024) = g;
}

// ---------------- GEMM: BN=64, dbuf BK=32, 3 blocks/CU ----------------
// grid (bn=4, bm=64, bz=nsplit), block 256 (4 waves 2x2), wave tile 64x32
// LDS/stage 24KB: A f32 [128][32] XOR(row&7)-swizzled (16KB) + W' chunk (8KB)
__global__ __launch_bounds__(256) void gemm16(
    const float* __restrict__ x, const char* __restrict__ wt,
    float* __restrict__ part, int ksplit) {
    __shared__ char smem[49152];
    const int tid = threadIdx.x;
    const int lane = tid & 63;
    const int wv = tid >> 6;
    const int bn = blockIdx.x, bm = blockIdx.y, bz = blockIdx.z;
    const int wr = wv >> 1, wcn = wv & 1;
    const int l15 = lane & 15, q4 = lane >> 4;
    const int niter = ksplit >> 5;

    const char* xc = (const char*)x;

    // A staging: 4 x 1KB gll per wave (R4-proven swizzle)
    int aoff[4], ldsA[4];
#pragma unroll
    for (int i = 0; i < 4; ++i) {
        const int ai = wv * 4 + i;
        const int ra = ai * 8 + (lane >> 3);
        const int ua = lane & 7;
        aoff[i] = (bm * 128 + ra) * (DIM * 4) + bz * (ksplit * 4)
                + ((ua ^ (ra & 7)) * 16);
        ldsA[i] = ai * 1024;
    }
    // W staging: 2 x 1KB linear gll per wave from pre-tiled image
    const char* wbase = wt + ((size_t)(bz * niter * 4 + bn)) * 8192;
    int woff[2], ldsW[2];
#pragma unroll
    for (int i = 0; i < 2; ++i) {
        const int unit = wv * 2 + i;
        woff[i] = unit * 1024 + lane * 16;
        ldsW[i] = 16384 + unit * 1024;
    }

    // A fragment-read byte offsets (R4-proven)
    int rA[4][2];
#pragma unroll
    for (int m = 0; m < 4; ++m) {
        const int r = wr * 64 + m * 16 + l15;
        rA[m][0] = r * 128 + (((2 * q4 + 0) ^ (r & 7)) * 16);
        rA[m][1] = r * 128 + (((2 * q4 + 1) ^ (r & 7)) * 16);
    }
    // W fragment-read offsets: [nt][plane]
    int rW[2][2];
#pragma unroll
    for (int nt = 0; nt < 2; ++nt)
#pragma unroll
        for (int p = 0; p < 2; ++p)
            rW[nt][p] = 16384 + (p * 4 + (wcn * 2 + nt)) * 1024 + q4 * 256 + l15 * 16;

    f32x4 acc[4][2];
#pragma unroll
    for (int m = 0; m < 4; ++m)
#pragma unroll
        for (int nt = 0; nt < 2; ++nt) acc[m][nt] = (f32x4){0.f, 0.f, 0.f, 0.f};

#define STAGE(sb)                                                               \
    {                                                                           \
        _Pragma("unroll")                                                       \
        for (int i = 0; i < 4; ++i)                                             \
            __builtin_amdgcn_global_load_lds((const AS1 void*)(xc + aoff[i]),   \
                (AS3 void*)(smem + (sb) + ldsA[i]), 16, 0, 0);                  \
        _Pragma("unroll")                                                       \
        for (int i = 0; i < 2; ++i)                                             \
            __builtin_amdgcn_global_load_lds((const AS1 void*)(wbase + woff[i]),\
                (AS3 void*)(smem + (sb) + ldsW[i]), 16, 0, 0);                  \
        _Pragma("unroll")                                                       \
        for (int i = 0; i < 4; ++i) aoff[i] += 128;                             \
        _Pragma("unroll")                                                       \
        for (int i = 0; i < 2; ++i) woff[i] += 32768;                           \
    }

#define COMPUTE(sb)                                                             \
    {                                                                           \
        f16x8 wb[2][2];                                                         \
        _Pragma("unroll")                                                       \
        for (int nt = 0; nt < 2; ++nt) {                                        \
            wb[nt][0] = *(const f16x8*)(smem + (sb) + rW[nt][0]);               \
            wb[nt][1] = *(const f16x8*)(smem + (sb) + rW[nt][1]);               \
        }                                                                       \
        _Pragma("unroll")                                                       \
        for (int m = 0; m < 4; ++m) {                                           \
            const f32x4 v0 = *(const f32x4*)(smem + (sb) + rA[m][0]);           \
            const f32x4 v1 = *(const f32x4*)(smem + (sb) + rA[m][1]);           \
            float c[8] = {v0[0]*4096.f, v0[1]*4096.f, v0[2]*4096.f, v0[3]*4096.f,\
                          v1[0]*4096.f, v1[1]*4096.f, v1[2]*4096.f, v1[3]*4096.f};\
            f16x8 a0, a1;                                                       \
            _Pragma("unroll")                                                   \
            for (int j = 0; j < 4; ++j) {                                       \
                h16x2 hp = __builtin_amdgcn_cvt_pkrtz(c[2*j], c[2*j+1]);        \
                float r0 = c[2*j]   - (float)hp[0];                             \
                float r1 = c[2*j+1] - (float)hp[1];                             \
                h16x2 gp = __builtin_amdgcn_cvt_pkrtz(r0, r1);                  \
                a0[2*j] = (f16)hp[0]; a0[2*j+1] = (f16)hp[1];                   \
                a1[2*j] = (f16)gp[0]; a1[2*j+1] = (f16)gp[1];                   \
            }                                                                   \
            __builtin_amdgcn_s_setprio(1);                                      \
            _Pragma("unroll")                                                   \
            for (int nt = 0; nt < 2; ++nt) {                                    \
                acc[m][nt] = __builtin_amdgcn_mfma_f32_16x16x32_f16(a0, wb[nt][0], acc[m][nt], 0, 0, 0); \
                acc[m][nt] = __builtin_amdgcn_mfma_f32_16x16x32_f16(a1, wb[nt][0], acc[m][nt], 0, 0, 0); \
                acc[m][nt] = __builtin_amdgcn_mfma_f32_16x16x32_f16(a0, wb[nt][1], acc[m][nt], 0, 0, 0); \
                acc[m][nt] = __builtin_amdgcn_mfma_f32_16x16x32_f16(a1, wb[nt][1], acc[m][nt], 0, 0, 0); \
            }                                                                   \
            __builtin_amdgcn_s_setprio(0);                                      \
        }                                                                       \
    }

    STAGE(0);
    for (int t = 0; t < niter - 1; ++t) {
        const int cur = (t & 1) * 24576;
        const int nxt = ((t + 1) & 1) * 24576;
        STAGE(nxt);                                  // 6 loads stay in flight
        asm volatile("s_waitcnt vmcnt(6)" ::: "memory");   // K-step t's 6 landed
        __builtin_amdgcn_sched_barrier(0);
        __builtin_amdgcn_s_barrier();
        COMPUTE(cur);
        __builtin_amdgcn_s_barrier();
    }
    asm volatile("s_waitcnt vmcnt(0)" ::: "memory");
    __builtin_amdgcn_sched_barrier(0);
    __builtin_amdgcn_s_barrier();
    COMPUTE(((niter - 1) & 1) * 24576);
#undef STAGE
#undef COMPUTE

    // epilogue (R4-proven C layout: col=l15, row=q4*4+r within 16x16 tile)
    float* P = part + (size_t)bz * T_TOKENS * NEXP;
    const int orow = bm * 128 + wr * 64 + q4 * 4;
#pragma unroll
    for (int m = 0; m < 4; ++m)
#pragma unroll
        for (int nt = 0; nt < 2; ++nt) {
            const int ocol = bn * 64 + (wcn * 2 + nt) * 16 + l15;
#pragma unroll
            for (int r = 0; r < 4; ++r)
                P[(size_t)(orow + m * 16 + r) * NEXP + ocol] = acc[m][nt][r];
        }
}

// ---------------- Routing: one wave per token (identical logic since R1) ----------------
__global__ __launch_bounds__(256) void routing_kernel(const float* __restrict__ part,
                                                      const float* __restrict__ bias,
                                                      float* __restrict__ out, int nsplit) {
    const int lane = threadIdx.x & 63;
    const int t = blockIdx.x * 4 + (threadIdx.x >> 6);

    f32x4 z = {0.f, 0.f, 0.f, 0.f};
    for (int s = 0; s < nsplit; ++s) {
        const f32x4 v = *((const f32x4*)(part + ((size_t)s * T_TOKENS + t) * NEXP) + lane);
        z[0] += v[0]; z[1] += v[1]; z[2] += v[2]; z[3] += v[3];
    }
    const float s0 = 1.0f / (1.0f + expf(-z[0] * UNSCALE));
    const float s1 = 1.0f / (1.0f + expf(-z[1] * UNSCALE));
    const float s2 = 1.0f / (1.0f + expf(-z[2] * UNSCALE));
    const float s3 = 1.0f / (1.0f + expf(-z[3] * UNSCALE));
    const f32x4 bv = *((const f32x4*)bias + lane);
    float sb0 = s0 + bv[0], sb1 = s1 + bv[1], sb2 = s2 + bv[2], sb3 = s3 + bv[3];

    float m1, m2;
    m1 = sb0; m2 = NEG_INF;
    if (sb1 > m1) { m2 = m1; m1 = sb1; } else if (sb1 > m2) m2 = sb1;
    if (sb2 > m1) { m2 = m1; m1 = sb2; } else if (sb2 > m2) m2 = sb2;
    if (sb3 > m1) { m2 = m1; m1 = sb3; } else if (sb3 > m2) m2 = sb3;
#pragma unroll
    for (int off = 1; off < 8; off <<= 1) {
        const float om1 = __shfl_xor(m1, off);
        const float om2 = __shfl_xor(m2, off);
        const float hi = fmaxf(m1, om1);
        const float lo = fminf(m1, om1);
        m2 = fmaxf(lo, fmaxf(m2, om2));
        m1 = hi;
    }
    const float gs = m1 + m2;

    const float g0 = __shfl(gs, 0),  g1 = __shfl(gs, 8),  g2 = __shfl(gs, 16), g3 = __shfl(gs, 24);
    const float g4 = __shfl(gs, 32), g5 = __shfl(gs, 40), g6 = __shfl(gs, 48), g7 = __shfl(gs, 56);

    float t1 = NEG_INF, t2 = NEG_INF, t3 = NEG_INF, t4 = NEG_INF;
    int i1 = 0, i2 = 0, i3 = 0, i4 = 0;
#define INS4(v, gi)                                                         \
    {                                                                       \
        if (v > t1)      { t4=t3;i4=i3; t3=t2;i3=i2; t2=t1;i2=i1; t1=v;i1=gi; } \
        else if (v > t2) { t4=t3;i4=i3; t3=t2;i3=i2; t2=v;i2=gi; }          \
        else if (v > t3) { t4=t3;i4=i3; t3=v;i3=gi; }                       \
        else if (v > t4) { t4=v;i4=gi; }                                    \
    }
    INS4(g0, 0) INS4(g1, 1) INS4(g2, 2) INS4(g3, 3)
    INS4(g4, 4) INS4(g5, 5) INS4(g6, 6) INS4(g7, 7)
#undef INS4
    const int keepmask = (1 << i1) | (1 << i2) | (1 << i3) | (1 << i4);

    const int g = lane >> 3;
    if (!((keepmask >> g) & 1)) { sb0 = NEG_INF; sb1 = NEG_INF; sb2 = NEG_INF; sb3 = NEG_INF; }

    float wval[8];
    int wi[8];
    float wsum = 0.0f;
#pragma unroll
    for (int r = 0; r < 8; r++) {
        float bvv = sb0;
        int bii = (lane << 2);
        if (sb1 > bvv) { bvv = sb1; bii = (lane << 2) | 1; }
        if (sb2 > bvv) { bvv = sb2; bii = (lane << 2) | 2; }
        if (sb3 > bvv) { bvv = sb3; bii = (lane << 2) | 3; }
#pragma unroll
        for (int off = 1; off < 64; off <<= 1) {
            const float ov = __shfl_xor(bvv, off);
            const int oi = __shfl_xor(bii, off);
            if (ov > bvv || (ov == bvv && oi < bii)) { bvv = ov; bii = oi; }
        }
        const int sl = bii & 3;
        const float cand = (sl == 0) ? s0 : (sl == 1) ? s1 : (sl == 2) ? s2 : s3;
        const float ow = __shfl(cand, bii >> 2);
        wval[r] = ow;
        wi[r] = bii;
        wsum += ow;
        if ((bii >> 2) == lane) {
            if (sl == 0) sb0 = NEG_INF;
            else if (sl == 1) sb1 = NEG_INF;
            else if (sl == 2) sb2 = NEG_INF;
            else sb3 = NEG_INF;
        }
    }
    const float scale = 2.5f / wsum;
    if (lane == 0) {
        float* ow8 = out + (size_t)t * 8;
        float* oi8 = out + (size_t)T_TOKENS * 8 + (size_t)t * 8;
#pragma unroll
        for (int r = 0; r < 8; r++) {
            ow8[r] = wval[r] * scale;
            oi8[r] = (float)wi[r];
        }
    }
}

extern "C" void kernel_launch(void* const* d_in, const int* in_sizes, int n_in,
                              void* d_out, int out_size, void* d_ws, size_t ws_size,
                              hipStream_t stream) {
    const float* x = (const float*)d_in[0];
    const float* w = (const float*)d_in[1];
    const float* bias = (const float*)d_in[2];

    char* wt = (char*)d_ws;
    float* part = (float*)((char*)d_ws + PART_OFF);

    const size_t need4 = (size_t)PART_OFF + 4ull * T_TOKENS * NEXP * 4;
    const int nsplit = (ws_size >= need4) ? 4 : 2;
    const int ksplit = DIM / nsplit;

    wconvert<<<NEXP * DIM / (256 * 8), 256, 0, stream>>>(w, wt);
    gemm16<<<dim3(4, 64, nsplit), 256, 0, stream>>>(x, wt, part, ksplit);
    routing_kernel<<<T_TOKENS / 4, 256, 0, stream>>>(part, bias, (float*)d_out, nsplit);
}

// Round 7
// 151.955 us; speedup vs baseline: 1.3080x; 1.1824x over previous
//
#include <hip/hip_runtime.h>
#include <math.h>

#define T_TOKENS 8192
#define NEXP 256
#define DIM 7168
#define NEG_INF (-3.0e38f)

typedef _Float16 f16;
typedef _Float16 f16x8 __attribute__((ext_vector_type(8)));
typedef __fp16 h16x2 __attribute__((ext_vector_type(2)));
typedef float f32x4 __attribute__((ext_vector_type(4)));

#define AS1 __attribute__((address_space(1)))
#define AS3 __attribute__((address_space(3)))

// ws layout: [W' frag-tiled f16 7.34MB][part f32 (nsplit x T x E)]
// W' 8KB chunks indexed by (T = k/32, bnq = expert/64):
//   off = (p*4 + nt)*1024 + q*256 + l*16   (p=plane, nt=(e>>4)&3, q=(k>>3)&3, l=e&15)
#define WTILED_BYTES (2 * NEXP * DIM * 2)      // 7,340,032
#define PART_OFF WTILED_BYTES
#define UNSCALE 5.9604644775390625e-8f         // 2^-24 exact

// ---------------- prologue: w (f32) -> frag-tiled 2-plane f16 image ----------------
__global__ __launch_bounds__(256) void wconvert(const float* __restrict__ w,
                                                char* __restrict__ wt) {
    const int n = blockIdx.x * 256 + threadIdx.x;   // 0 .. 229375
    const int K8 = n % 896;                         // k-octet
    const int e = n / 896;                          // expert 0..255
    const f32x4 u0 = *(const f32x4*)(w + (size_t)e * DIM + K8 * 8);
    const f32x4 u1 = *(const f32x4*)(w + (size_t)e * DIM + K8 * 8 + 4);
    float c[8] = {u0[0]*4096.f, u0[1]*4096.f, u0[2]*4096.f, u0[3]*4096.f,
                  u1[0]*4096.f, u1[1]*4096.f, u1[2]*4096.f, u1[3]*4096.f};
    f16x8 h, g;
#pragma unroll
    for (int j = 0; j < 4; ++j) {
        h16x2 hp = __builtin_amdgcn_cvt_pkrtz(c[2*j], c[2*j+1]);
        float r0 = c[2*j]   - (float)hp[0];
        float r1 = c[2*j+1] - (float)hp[1];
        h16x2 gp = __builtin_amdgcn_cvt_pkrtz(r0, r1);
        h[2*j] = (f16)hp[0]; h[2*j+1] = (f16)hp[1];
        g[2*j] = (f16)gp[0]; g[2*j+1] = (f16)gp[1];
    }
    const int T = K8 >> 2, q = K8 & 3;
    const int bnq = e >> 6, nt = (e >> 4) & 3, l = e & 15;
    char* base = wt + ((size_t)(T * 4 + bnq)) * 8192 + q * 256 + l * 16;
    *(f16x8*)(base + (0 * 4 + nt) * 1024) = h;
    *(f16x8*)(base + (1 * 4 + nt) * 1024) = g;
}

// ---------------- GEMM: 512-thread blocks, tile 128x128, dbuf BK=32 ----------------
// grid (bn=2, bm=64, bz=nsplit) = 512 blocks = exactly 2 blocks/CU (16 waves/CU)
// 8 waves as 2(wr) x 4(wcn); wave tile 64x32.
// LDS/stage 32KB: A f32 [128][32] XOR(row&7) swizzle (16KB) + W' 2 chunks (16KB)
__global__ __launch_bounds__(512) void gemm8w(
    const float* __restrict__ x, const char* __restrict__ wt,
    float* __restrict__ part, int ksplit) {
    __shared__ char smem[65536];
    const int tid = threadIdx.x;
    const int lane = tid & 63;
    const int wv = tid >> 6;                 // 0..7
    const int bn = blockIdx.x, bm = blockIdx.y, bz = blockIdx.z;
    const int wr = wv >> 2, wcn = wv & 3;    // 2 x 4 wave grid
    const int l15 = lane & 15, q4 = lane >> 4;
    const int niter = ksplit >> 5;

    const char* xc = (const char*)x;

    // A staging: 2 x 1KB gll per wave (16 units cover 128 rows x 32 k f32)
    int aoff[2], ldsA[2];
#pragma unroll
    for (int i = 0; i < 2; ++i) {
        const int u = wv * 2 + i;
        const int ra = u * 8 + (lane >> 3);
        const int ua = lane & 7;
        aoff[i] = (bm * 128 + ra) * (DIM * 4) + bz * (ksplit * 4)
                + ((ua ^ (ra & 7)) * 16);
        ldsA[i] = u * 1024;
    }
    // W staging: 2 x 1KB linear gll per wave (two consecutive 8KB chunks)
    const char* wbase0 = wt + ((size_t)(bz * niter * 4 + bn * 2)) * 8192;
    int woff[2], ldsW[2];
#pragma unroll
    for (int i = 0; i < 2; ++i) {
        const int u = wv * 2 + i;
        woff[i] = u * 1024 + lane * 16;
        ldsW[i] = 16384 + u * 1024;
    }

    // A fragment-read byte offsets (proven swizzle)
    int rA[4][2];
#pragma unroll
    for (int m = 0; m < 4; ++m) {
        const int r = wr * 64 + m * 16 + l15;
        rA[m][0] = r * 128 + (((2 * q4 + 0) ^ (r & 7)) * 16);
        rA[m][1] = r * 128 + (((2 * q4 + 1) ^ (r & 7)) * 16);
    }
    // W fragment-read offsets: [ntl][plane]
    int rW[2][2];
#pragma unroll
    for (int ntl = 0; ntl < 2; ++ntl)
#pragma unroll
        for (int p = 0; p < 2; ++p)
            rW[ntl][p] = 16384 + (wcn >> 1) * 8192
                       + (p * 4 + (wcn & 1) * 2 + ntl) * 1024 + q4 * 256 + l15 * 16;

    f32x4 acc[4][2];
#pragma unroll
    for (int m = 0; m < 4; ++m)
#pragma unroll
        for (int ntl = 0; ntl < 2; ++ntl) acc[m][ntl] = (f32x4){0.f, 0.f, 0.f, 0.f};

#define STAGE(sb)                                                               \
    {                                                                           \
        _Pragma("unroll")                                                       \
        for (int i = 0; i < 2; ++i)                                             \
            __builtin_amdgcn_global_load_lds((const AS1 void*)(xc + aoff[i]),   \
                (AS3 void*)(smem + (sb) + ldsA[i]), 16, 0, 0);                  \
        _Pragma("unroll")                                                       \
        for (int i = 0; i < 2; ++i)                                             \
            __builtin_amdgcn_global_load_lds((const AS1 void*)(wbase0 + woff[i]),\
                (AS3 void*)(smem + (sb) + ldsW[i]), 16, 0, 0);                  \
        _Pragma("unroll")                                                       \
        for (int i = 0; i < 2; ++i) { aoff[i] += 128; woff[i] += 32768; }       \
    }

#define COMPUTE(sb)                                                             \
    {                                                                           \
        f16x8 wb[2][2];                                                         \
        _Pragma("unroll")                                                       \
        for (int ntl = 0; ntl < 2; ++ntl) {                                     \
            wb[ntl][0] = *(const f16x8*)(smem + (sb) + rW[ntl][0]);             \
            wb[ntl][1] = *(const f16x8*)(smem + (sb) + rW[ntl][1]);             \
        }                                                                       \
        _Pragma("unroll")                                                       \
        for (int m = 0; m < 4; ++m) {                                           \
            const f32x4 v0 = *(const f32x4*)(smem + (sb) + rA[m][0]);           \
            const f32x4 v1 = *(const f32x4*)(smem + (sb) + rA[m][1]);           \
            float c[8] = {v0[0]*4096.f, v0[1]*4096.f, v0[2]*4096.f, v0[3]*4096.f,\
                          v1[0]*4096.f, v1[1]*4096.f, v1[2]*4096.f, v1[3]*4096.f};\
            f16x8 a0, a1;                                                       \
            _Pragma("unroll")                                                   \
            for (int j = 0; j < 4; ++j) {                                       \
                h16x2 hp = __builtin_amdgcn_cvt_pkrtz(c[2*j], c[2*j+1]);        \
                float r0 = c[2*j]   - (float)hp[0];                             \
                float r1 = c[2*j+1] - (float)hp[1];                             \
                h16x2 gp = __builtin_amdgcn_cvt_pkrtz(r0, r1);                  \
                a0[2*j] = (f16)hp[0]; a0[2*j+1] = (f16)hp[1];                   \
                a1[2*j] = (f16)gp[0]; a1[2*j+1] = (f16)gp[1];                   \
            }                                                                   \
            __builtin_amdgcn_s_setprio(1);                                      \
            _Pragma("unroll")                                                   \
            for (int ntl = 0; ntl < 2; ++ntl) {                                 \
                acc[m][ntl] = __builtin_amdgcn_mfma_f32_16x16x32_f16(a0, wb[ntl][0], acc[m][ntl], 0, 0, 0); \
                acc[m][ntl] = __builtin_amdgcn_mfma_f32_16x16x32_f16(a1, wb[ntl][0], acc[m][ntl], 0, 0, 0); \
                acc[m][ntl] = __builtin_amdgcn_mfma_f32_16x16x32_f16(a0, wb[ntl][1], acc[m][ntl], 0, 0, 0); \
                acc[m][ntl] = __builtin_amdgcn_mfma_f32_16x16x32_f16(a1, wb[ntl][1], acc[m][ntl], 0, 0, 0); \
            }                                                                   \
            __builtin_amdgcn_s_setprio(0);                                      \
        }                                                                       \
    }

    STAGE(0);
    for (int t = 0; t < niter - 1; ++t) {
        const int cur = (t & 1) * 32768;
        const int nxt = ((t + 1) & 1) * 32768;
        STAGE(nxt);                                  // next stage's 4 loads stay in flight
        asm volatile("s_waitcnt vmcnt(4)" ::: "memory");   // K-step t's 4 landed
        __builtin_amdgcn_sched_barrier(0);
        __builtin_amdgcn_s_barrier();
        COMPUTE(cur);
        __builtin_amdgcn_s_barrier();
    }
    asm volatile("s_waitcnt vmcnt(0)" ::: "memory");
    __builtin_amdgcn_sched_barrier(0);
    __builtin_amdgcn_s_barrier();
    COMPUTE(((niter - 1) & 1) * 32768);
#undef STAGE
#undef COMPUTE

    // epilogue (proven C layout: col=l15, row=q4*4+r within 16x16 tile)
    float* P = part + (size_t)bz * T_TOKENS * NEXP;
    const int orow = bm * 128 + wr * 64 + q4 * 4;
#pragma unroll
    for (int m = 0; m < 4; ++m)
#pragma unroll
        for (int ntl = 0; ntl < 2; ++ntl) {
            const int ocol = bn * 128 + wcn * 32 + ntl * 16 + l15;
#pragma unroll
            for (int r = 0; r < 4; ++r)
                P[(size_t)(orow + m * 16 + r) * NEXP + ocol] = acc[m][ntl][r];
        }
}

// ---------------- Routing: one wave per token (identical logic since R1) ----------------
__global__ __launch_bounds__(256) void routing_kernel(const float* __restrict__ part,
                                                      const float* __restrict__ bias,
                                                      float* __restrict__ out, int nsplit) {
    const int lane = threadIdx.x & 63;
    const int t = blockIdx.x * 4 + (threadIdx.x >> 6);

    f32x4 z = {0.f, 0.f, 0.f, 0.f};
    for (int s = 0; s < nsplit; ++s) {
        const f32x4 v = *((const f32x4*)(part + ((size_t)s * T_TOKENS + t) * NEXP) + lane);
        z[0] += v[0]; z[1] += v[1]; z[2] += v[2]; z[3] += v[3];
    }
    const float s0 = 1.0f / (1.0f + expf(-z[0] * UNSCALE));
    const float s1 = 1.0f / (1.0f + expf(-z[1] * UNSCALE));
    const float s2 = 1.0f / (1.0f + expf(-z[2] * UNSCALE));
    const float s3 = 1.0f / (1.0f + expf(-z[3] * UNSCALE));
    const f32x4 bv = *((const f32x4*)bias + lane);
    float sb0 = s0 + bv[0], sb1 = s1 + bv[1], sb2 = s2 + bv[2], sb3 = s3 + bv[3];

    float m1, m2;
    m1 = sb0; m2 = NEG_INF;
    if (sb1 > m1) { m2 = m1; m1 = sb1; } else if (sb1 > m2) m2 = sb1;
    if (sb2 > m1) { m2 = m1; m1 = sb2; } else if (sb2 > m2) m2 = sb2;
    if (sb3 > m1) { m2 = m1; m1 = sb3; } else if (sb3 > m2) m2 = sb3;
#pragma unroll
    for (int off = 1; off < 8; off <<= 1) {
        const float om1 = __shfl_xor(m1, off);
        const float om2 = __shfl_xor(m2, off);
        const float hi = fmaxf(m1, om1);
        const float lo = fminf(m1, om1);
        m2 = fmaxf(lo, fmaxf(m2, om2));
        m1 = hi;
    }
    const float gs = m1 + m2;

    const float g0 = __shfl(gs, 0),  g1 = __shfl(gs, 8),  g2 = __shfl(gs, 16), g3 = __shfl(gs, 24);
    const float g4 = __shfl(gs, 32), g5 = __shfl(gs, 40), g6 = __shfl(gs, 48), g7 = __shfl(gs, 56);

    float t1 = NEG_INF, t2 = NEG_INF, t3 = NEG_INF, t4 = NEG_INF;
    int i1 = 0, i2 = 0, i3 = 0, i4 = 0;
#define INS4(v, gi)                                                         \
    {                                                                       \
        if (v > t1)      { t4=t3;i4=i3; t3=t2;i3=i2; t2=t1;i2=i1; t1=v;i1=gi; } \
        else if (v > t2) { t4=t3;i4=i3; t3=t2;i3=i2; t2=v;i2=gi; }          \
        else if (v > t3) { t4=t3;i4=i3; t3=v;i3=gi; }                       \
        else if (v > t4) { t4=v;i4=gi; }                                    \
    }
    INS4(g0, 0) INS4(g1, 1) INS4(g2, 2) INS4(g3, 3)
    INS4(g4, 4) INS4(g5, 5) INS4(g6, 6) INS4(g7, 7)
#undef INS4
    const int keepmask = (1 << i1) | (1 << i2) | (1 << i3) | (1 << i4);

    const int g = lane >> 3;
    if (!((keepmask >> g) & 1)) { sb0 = NEG_INF; sb1 = NEG_INF; sb2 = NEG_INF; sb3 = NEG_INF; }

    float wval[8];
    int wi[8];
    float wsum = 0.0f;
#pragma unroll
    for (int r = 0; r < 8; r++) {
        float bvv = sb0;
        int bii = (lane << 2);
        if (sb1 > bvv) { bvv = sb1; bii = (lane << 2) | 1; }
        if (sb2 > bvv) { bvv = sb2; bii = (lane << 2) | 2; }
        if (sb3 > bvv) { bvv = sb3; bii = (lane << 2) | 3; }
#pragma unroll
        for (int off = 1; off < 64; off <<= 1) {
            const float ov = __shfl_xor(bvv, off);
            const int oi = __shfl_xor(bii, off);
            if (ov > bvv || (ov == bvv && oi < bii)) { bvv = ov; bii = oi; }
        }
        const int sl = bii & 3;
        const float cand = (sl == 0) ? s0 : (sl == 1) ? s1 : (sl == 2) ? s2 : s3;
        const float ow = __shfl(cand, bii >> 2);
        wval[r] = ow;
        wi[r] = bii;
        wsum += ow;
        if ((bii >> 2) == lane) {
            if (sl == 0) sb0 = NEG_INF;
            else if (sl == 1) sb1 = NEG_INF;
            else if (sl == 2) sb2 = NEG_INF;
            else sb3 = NEG_INF;
        }
    }
    const float scale = 2.5f / wsum;
    if (lane == 0) {
        float* ow8 = out + (size_t)t * 8;
        float* oi8 = out + (size_t)T_TOKENS * 8 + (size_t)t * 8;
#pragma unroll
        for (int r = 0; r < 8; r++) {
            ow8[r] = wval[r] * scale;
            oi8[r] = (float)wi[r];
        }
    }
}

extern "C" void kernel_launch(void* const* d_in, const int* in_sizes, int n_in,
                              void* d_out, int out_size, void* d_ws, size_t ws_size,
                              hipStream_t stream) {
    const float* x = (const float*)d_in[0];
    const float* w = (const float*)d_in[1];
    const float* bias = (const float*)d_in[2];

    char* wt = (char*)d_ws;
    float* part = (float*)((char*)d_ws + PART_OFF);

    const size_t need4 = (size_t)PART_OFF + 4ull * T_TOKENS * NEXP * 4;
    const int nsplit = (ws_size >= need4) ? 4 : 2;
    const int ksplit = DIM / nsplit;

    wconvert<<<NEXP * DIM / (256 * 8), 256, 0, stream>>>(w, wt);
    gemm8w<<<dim3(2, 64, nsplit), 512, 0, stream>>>(x, wt, part, ksplit);
    routing_kernel<<<T_TOKENS / 4, 256, 0, stream>>>(part, bias, (float*)d_out, nsplit);
}